// Round 5
// baseline (10298.915 us; speedup 1.0000x reference)
//
#include <hip/hip_runtime.h>
#include <hip/hip_bf16.h>

typedef __attribute__((ext_vector_type(4))) float  f32x4;
typedef __attribute__((ext_vector_type(8))) __bf16 bf16x8;

#define H_DIM 256
#define SEQ   64
#define TDEC  32
#define BB    16
#define NTH   512

// ws layout (bf16 element offsets). Six big matrices stored in MFMA-fragment
// order: elem = w*32768 + k0i*4096 + gs*512 + lane*8 + e
//   row = g*256 + st*16 + w*32 + (lane&15), col = k0i*32 + (lane>>4)*8 + e
#define OW0 0u         // enc_Whh0
#define OW1 262144u    // enc_Wih1
#define OW2 524288u    // enc_Whh1
#define OW3 786432u    // dec_Whh0
#define OW4 1048576u   // dec_Wih1
#define OW5 1310720u   // dec_Whh1
#define OW6 1572864u   // Wp1: w*4096 + k0i*512 + lane*8 + e ; row=w*16+(lane&15)
#define OW7 1605632u   // Wp2 padded [16][128]: k0i*512 + lane*8 + e ; row=lane&15
#define WS_ELEMS 1607680u

__global__ void prep_kernel(const float* __restrict__ s0, const float* __restrict__ s1,
                            const float* __restrict__ s2, const float* __restrict__ s3,
                            const float* __restrict__ s4, const float* __restrict__ s5,
                            const float* __restrict__ s6, const float* __restrict__ s7,
                            ushort* __restrict__ o) {
  unsigned i = blockIdx.x * 256u + threadIdx.x;
  if (i >= WS_ELEMS) return;
  float v;
  if (i < OW6) {
    unsigned m = i >> 18, r = i & 262143u;
    unsigned w = r >> 15, r2 = r & 32767u;
    unsigned k0i = r2 >> 12, r3 = r2 & 4095u;
    unsigned gs = r3 >> 9, r4 = r3 & 511u;
    unsigned lane = r4 >> 3, e = r4 & 7u;
    unsigned row = (gs >> 1) * 256u + (gs & 1u) * 16u + w * 32u + (lane & 15u);
    unsigned colk = k0i * 32u + (lane >> 4) * 8u + e;
    const float* s = (m==0)?s0:(m==1)?s1:(m==2)?s2:(m==3)?s3:(m==4)?s4:s5;
    v = s[row * 256u + colk];
  } else if (i < OW7) {
    unsigned r = i - OW6;
    unsigned w = r >> 12, r2 = r & 4095u;
    unsigned k0i = r2 >> 9, r3 = r2 & 511u;
    unsigned lane = r3 >> 3, e = r3 & 7u;
    unsigned row = w * 16u + (lane & 15u);
    unsigned colk = k0i * 32u + (lane >> 4) * 8u + e;
    v = s6[row * 256u + colk];
  } else {
    unsigned r = i - OW7;
    unsigned k0i = r >> 9, r3 = r & 511u;
    unsigned lane = r3 >> 3, e = r3 & 7u;
    unsigned row = lane & 15u;
    unsigned colk = k0i * 32u + (lane >> 4) * 8u + e;
    v = (row < 4u) ? s7[row * 128u + colk] : 0.0f;
  }
  __bf16 b = (__bf16)v;
  o[i] = __builtin_bit_cast(ushort, b);
}

__device__ __forceinline__ float sig_(float x) {
  return __builtin_amdgcn_rcpf(1.0f + __expf(-x));
}
__device__ __forceinline__ float tanh_(float x) {
  return 1.0f - 2.0f * __builtin_amdgcn_rcpf(__expf(2.0f*x) + 1.0f);
}
// 32-slot swizzle: granule u of row stored at slot (u + 4*(row&7)) & 31.
__device__ __forceinline__ int swz32(int row, int n) {
  return row*H_DIM + ((((n >> 3) + 4*(row & 7)) & 31) << 3) + (n & 7);
}
__device__ __forceinline__ bf16x8 ldh(const ushort* buf, int row, int u) {
  return *(const bf16x8*)(buf + row*H_DIM + (((u + 4*(row & 7)) & 31) << 3));
}

// load one 8-fragment weight chunk (wave-contiguous 1KB x 8); fixed-trip-8 loop
// always fully unrolls -> static indices only
#define LDARR(dst, Bb, k0i) { _Pragma("unroll") \
  for (int g = 0; g < 8; ++g) (dst)[g] = *(const bf16x8*)((Bb) + (k0i)*4096 + g*512); }
#define MFMA8(acc, af, src) { _Pragma("unroll") \
  for (int g = 0; g < 8; ++g) (acc)[g] = __builtin_amdgcn_mfma_f32_16x16x32_bf16((af), (src)[g], (acc)[g], 0, 0, 0); }

#define GATES(accv, cst, dst) { _Pragma("unroll") \
  for (int st = 0; st < 2; ++st) { _Pragma("unroll") \
    for (int r = 0; r < 4; ++r) { \
      float iv = sig_((accv)[0+st][r]); \
      float fv = sig_((accv)[2+st][r]); \
      float gv = tanh_((accv)[4+st][r]); \
      float ov = sig_((accv)[6+st][r]); \
      float cn = fv*(cst)[st][r] + iv*gv; \
      (cst)[st][r] = cn; \
      float hn = ov*tanh_(cn); \
      __bf16 hb = (__bf16)hn; \
      (dst)[swz32(quad*4+r, st*16 + n0)] = __builtin_bit_cast(ushort, hb); \
    } } }

__global__ __launch_bounds__(NTH, 2) void lstm_all(
    const float* __restrict__ x,
    const float* __restrict__ eWih0, const float* __restrict__ eb0, const float* __restrict__ eb1,
    const float* __restrict__ dWih0, const float* __restrict__ db0, const float* __restrict__ db1,
    const float* __restrict__ bp1, const float* __restrict__ bp2,
    const ushort* __restrict__ ws,
    float* __restrict__ out)
{
  const int tid  = threadIdx.x;
  const int wv   = tid >> 6;
  const int lane = tid & 63;
  const int col  = lane & 15;
  const int quad = lane >> 4;
  const int blk  = blockIdx.x;
  const int n0   = wv*32 + col;
  const int rot  = blk & 7;

  __shared__ __align__(16) ushort sh_h0[2][BB*H_DIM];
  __shared__ __align__(16) ushort sh_h1[2][BB*H_DIM];
  __shared__ __align__(16) ushort sh_r[BB*H_DIM];
  __shared__ __align__(16) float  sh_x[SEQ*BB*4];   // [t][b][k]
  __shared__ __align__(16) float  sh_pred[BB*4];

  for (int i = tid; i < SEQ*BB*4; i += NTH) {
    int b = i >> 8, tk = i & 255;
    sh_x[(tk>>2)*64 + b*4 + (tk&3)] = x[blk*(SEQ*BB*4) + i];
  }
  for (int i = tid; i < BB*H_DIM; i += NTH) {
    sh_h0[0][i]=0; sh_h0[1][i]=0; sh_h1[0][i]=0; sh_h1[1][i]=0;
  }
  __syncthreads();

  float c0[2][4] = {{0,0,0,0},{0,0,0,0}};
  float c1[2][4] = {{0,0,0,0},{0,0,0,0}};
  int cur = 0;

  const ushort* B0 = ws + OW0 + wv*32768 + lane*8;
  const ushort* B1 = ws + OW1 + wv*32768 + lane*8;
  const ushort* B2 = ws + OW2 + wv*32768 + lane*8;
  const ushort* B3 = ws + OW3 + wv*32768 + lane*8;
  const ushort* B4 = ws + OW4 + wv*32768 + lane*8;
  const ushort* B5 = ws + OW5 + wv*32768 + lane*8;
  const ushort* B6 = ws + OW6 + wv*4096  + lane*8;
  const ushort* B7 = ws + OW7 + lane*8;

  bf16x8 pwa[8];   // cross-step prefetch (phase-A first chunk)
  bf16x8 pwb[8];   // cross-barrier prefetch (phase-B first chunk)

  // ================= ENCODER =================
  {
    float eb0v[8], eb1v[8];
    #pragma unroll
    for (int gs = 0; gs < 8; ++gs) {
      int j = (gs>>1)*256 + (gs&1)*16 + n0;
      eb0v[gs] = eb0[j];
      eb1v[gs] = eb1[j];
    }
    LDARR(pwa, B0, rot);   // prologue: step-0 phase-A chunk 0

    for (int t = 0; t < SEQ; ++t) {
      const ushort* h0c = sh_h0[cur];
      // acc init from x-projection (VALU; overlaps pwa in flight)
      f32x4 acc[8];
      {
        f32x4 xv[4];
        #pragma unroll
        for (int r = 0; r < 4; ++r)
          xv[r] = *(const f32x4*)(sh_x + t*64 + (quad*4+r)*4);
        #pragma unroll
        for (int gs = 0; gs < 8; ++gs) {
          int j = (gs>>1)*256 + (gs&1)*16 + n0;
          f32x4 wvv = *(const f32x4*)(eWih0 + j*4);
          float bz = eb0v[gs];
          #pragma unroll
          for (int r = 0; r < 4; ++r)
            acc[gs][r] = bz + wvv[0]*xv[r][0] + wvv[1]*xv[r][1]
                            + wvv[2]*xv[r][2] + wvv[3]*xv[r][3];
        }
      }
      // ---- phase A: layer0 (B0 x h0c), chunk 0 from prefetch ----
      {
        bf16x8 af = ldh(h0c, col, rot*4 + quad);
        MFMA8(acc, af, pwa);
      }
      #pragma unroll
      for (int it = 1; it < 8; ++it) {
        int k0i = (it + rot) & 7;
        bf16x8 bw[8]; LDARR(bw, B0, k0i);
        bf16x8 af = ldh(h0c, col, k0i*4 + quad);
        MFMA8(acc, af, bw);
      }
      LDARR(pwb, B1, rot);   // prefetch across gates+barrier
      ushort* h0n = sh_h0[cur^1];
      GATES(acc, c0, h0n);
      __syncthreads();

      // ---- phase B: layer1 (B1 x h0n, B2 x h1c) ----
      f32x4 acc1[8];
      #pragma unroll
      for (int gs = 0; gs < 8; ++gs) {
        float bz = eb1v[gs];
        f32x4 v; v[0]=bz; v[1]=bz; v[2]=bz; v[3]=bz;
        acc1[gs] = v;
      }
      {
        bf16x8 af = ldh(h0n, col, rot*4 + quad);
        MFMA8(acc1, af, pwb);
      }
      #pragma unroll
      for (int it = 1; it < 8; ++it) {
        int k0i = (it + rot) & 7;
        bf16x8 bw[8]; LDARR(bw, B1, k0i);
        bf16x8 af = ldh(h0n, col, k0i*4 + quad);
        MFMA8(acc1, af, bw);
      }
      const ushort* h1c = sh_h1[cur];
      #pragma unroll
      for (int it = 0; it < 8; ++it) {
        int k0i = (it + rot) & 7;
        bf16x8 bw[8]; LDARR(bw, B2, k0i);
        bf16x8 af = ldh(h1c, col, k0i*4 + quad);
        MFMA8(acc1, af, bw);
      }
      LDARR(pwa, B0, rot);   // prefetch next step's phase-A chunk 0
      ushort* h1n = sh_h1[cur^1];
      GATES(acc1, c1, h1n);
      cur ^= 1;
    }
  }

  // ================= DECODER =================
  if (tid < 64) sh_pred[tid] = sh_x[63*64 + tid];
  __syncthreads();

  {
    float db0v[8], db1v[8];
    #pragma unroll
    for (int gs = 0; gs < 8; ++gs) {
      int j = (gs>>1)*256 + (gs&1)*16 + n0;
      db0v[gs] = db0[j];
      db1v[gs] = db1[j];
    }
    const float bz1 = bp1[wv*16 + col];
    LDARR(pwa, B3, rot);   // re-prime for decoder stream

    for (int t = 0; t < TDEC; ++t) {
      const ushort* h0c = sh_h0[cur];
      f32x4 acc[8];
      {
        f32x4 pv[4];
        #pragma unroll
        for (int r = 0; r < 4; ++r)
          pv[r] = *(const f32x4*)(sh_pred + (quad*4+r)*4);
        #pragma unroll
        for (int gs = 0; gs < 8; ++gs) {
          int j = (gs>>1)*256 + (gs&1)*16 + n0;
          f32x4 wvv = *(const f32x4*)(dWih0 + j*4);
          float bz = db0v[gs];
          #pragma unroll
          for (int r = 0; r < 4; ++r)
            acc[gs][r] = bz + wvv[0]*pv[r][0] + wvv[1]*pv[r][1]
                            + wvv[2]*pv[r][2] + wvv[3]*pv[r][3];
        }
      }
      // ---- phase A: layer0 (B3 x h0c), chunk 0 from prefetch ----
      {
        bf16x8 af = ldh(h0c, col, rot*4 + quad);
        MFMA8(acc, af, pwa);
      }
      #pragma unroll
      for (int it = 1; it < 8; ++it) {
        int k0i = (it + rot) & 7;
        bf16x8 bw[8]; LDARR(bw, B3, k0i);
        bf16x8 af = ldh(h0c, col, k0i*4 + quad);
        MFMA8(acc, af, bw);
      }
      LDARR(pwb, B4, rot);   // prefetch across gates+barrier
      ushort* h0n = sh_h0[cur^1];
      GATES(acc, c0, h0n);
      __syncthreads();

      // ---- phase B: layer1 (B4 x h0n, B5 x h1c) ----
      f32x4 acc1[8];
      #pragma unroll
      for (int gs = 0; gs < 8; ++gs) {
        float bz = db1v[gs];
        f32x4 v; v[0]=bz; v[1]=bz; v[2]=bz; v[3]=bz;
        acc1[gs] = v;
      }
      {
        bf16x8 af = ldh(h0n, col, rot*4 + quad);
        MFMA8(acc1, af, pwb);
      }
      #pragma unroll
      for (int it = 1; it < 8; ++it) {
        int k0i = (it + rot) & 7;
        bf16x8 bw[8]; LDARR(bw, B4, k0i);
        bf16x8 af = ldh(h0n, col, k0i*4 + quad);
        MFMA8(acc1, af, bw);
      }
      const ushort* h1c = sh_h1[cur];
      #pragma unroll
      for (int it = 0; it < 8; ++it) {
        int k0i = (it + rot) & 7;
        bf16x8 bw[8]; LDARR(bw, B5, k0i);
        bf16x8 af = ldh(h1c, col, k0i*4 + quad);
        MFMA8(acc1, af, bw);
      }
      LDARR(pwa, B3, rot);   // prefetch next step (lives across MLP barriers)
      ushort* h1n = sh_h1[cur^1];
      GATES(acc1, c1, h1n);
      __syncthreads();

      // ---- MLP layer 1 (B6): fragments issued up-front ----
      {
        bf16x8 wp[8];
        #pragma unroll
        for (int j = 0; j < 8; ++j)
          wp[j] = *(const bf16x8*)(B6 + ((j+rot)&7)*512);
        f32x4 accp; accp[0]=bz1; accp[1]=bz1; accp[2]=bz1; accp[3]=bz1;
        #pragma unroll
        for (int j = 0; j < 8; ++j) {
          int k0i = (j+rot)&7;
          bf16x8 af = ldh(h1n, col, k0i*4 + quad);
          accp = __builtin_amdgcn_mfma_f32_16x16x32_bf16(af, wp[j], accp, 0, 0, 0);
        }
        #pragma unroll
        for (int r = 0; r < 4; ++r) {
          float rv = fmaxf(accp[r], 0.0f);
          __bf16 rb = (__bf16)rv;
          sh_r[swz32(quad*4+r, wv*16 + col)] = __builtin_bit_cast(ushort, rb);
        }
      }
      __syncthreads();

      // ---- MLP layer 2 (wave 0 only, B7) ----
      if (wv == 0) {
        bf16x8 wq[4];
        #pragma unroll
        for (int j = 0; j < 4; ++j)
          wq[j] = *(const bf16x8*)(B7 + ((j+rot)&3)*512);
        f32x4 accq; accq[0]=0; accq[1]=0; accq[2]=0; accq[3]=0;
        #pragma unroll
        for (int j = 0; j < 4; ++j) {
          int k0i = (j+rot)&3;
          bf16x8 af = ldh(sh_r, col, k0i*4 + quad);
          accq = __builtin_amdgcn_mfma_f32_16x16x32_bf16(af, wq[j], accq, 0, 0, 0);
        }
        if (col < 4) {
          float bo = bp2[col];
          #pragma unroll
          for (int r = 0; r < 4; ++r) {
            float p = sig_(accq[r] + bo);
            int b = quad*4 + r;
            sh_pred[b*4 + col] = p;
            out[((blk*BB + b)*TDEC + t)*4 + col] = p;
          }
        }
      }
      __syncthreads();
      cur ^= 1;
    }
  }
}

extern "C" void kernel_launch(void* const* d_in, const int* in_sizes, int n_in,
                              void* d_out, int out_size, void* d_ws, size_t ws_size,
                              hipStream_t stream) {
  (void)in_sizes; (void)n_in; (void)out_size;
  if (ws_size < (size_t)WS_ELEMS * sizeof(ushort)) return;

  const float* x      = (const float*)d_in[0];
  const float* eWih0  = (const float*)d_in[1];
  const float* eWhh0  = (const float*)d_in[2];
  const float* eb0    = (const float*)d_in[3];
  const float* eWih1  = (const float*)d_in[4];
  const float* eWhh1  = (const float*)d_in[5];
  const float* eb1    = (const float*)d_in[6];
  const float* dWih0  = (const float*)d_in[7];
  const float* dWhh0  = (const float*)d_in[8];
  const float* db0    = (const float*)d_in[9];
  const float* dWih1  = (const float*)d_in[10];
  const float* dWhh1  = (const float*)d_in[11];
  const float* db1    = (const float*)d_in[12];
  const float* Wp1    = (const float*)d_in[13];
  const float* bp1    = (const float*)d_in[14];
  const float* Wp2    = (const float*)d_in[15];
  const float* bp2    = (const float*)d_in[16];
  ushort* ws = (ushort*)d_ws;

  prep_kernel<<<WS_ELEMS/256, 256, 0, stream>>>(eWhh0, eWih1, eWhh1, dWhh0, dWih1, dWhh1,
                                                Wp1, Wp2, ws);
  lstm_all<<<256, NTH, 0, stream>>>(x, eWih0, eb0, eb1, dWih0, db0, db1,
                                    bp1, bp2, ws, (float*)d_out);
}

// Round 6
// 1456.413 us; speedup vs baseline: 7.0714x; 7.0714x over previous
//
#include <hip/hip_runtime.h>
#include <hip/hip_bf16.h>

typedef __attribute__((ext_vector_type(4))) float  f32x4;
typedef __attribute__((ext_vector_type(8))) __bf16 bf16x8;

#define H_DIM 256
#define SEQ   64
#define TDEC  32
#define BB    16
#define NTH   1024

// ws layout (bf16 element offsets). Six big matrices stored in MFMA-fragment
// order: elem = w*32768 + k0i*4096 + gs*512 + lane*8 + e
//   row = (gs>>1)*256 + (gs&1)*16 + w*32 + (lane&15), col = k0i*32 + (lane>>4)*8 + e
// 16-wave view: w = wv>>1, gs = g*2 + (wv&1)  ->  row = g*256 + wv*16 + (lane&15)
#define OW0 0u         // enc_Whh0
#define OW1 262144u    // enc_Wih1
#define OW2 524288u    // enc_Whh1
#define OW3 786432u    // dec_Whh0
#define OW4 1048576u   // dec_Wih1
#define OW5 1310720u   // dec_Whh1
#define OW6 1572864u   // Wp1: w*4096 + k0i*512 + lane*8 + e ; row=w*16+(lane&15)
#define OW7 1605632u   // Wp2 padded [16][128]: k0i*512 + lane*8 + e ; row=lane&15
#define WS_ELEMS 1607680u

__global__ void prep_kernel(const float* __restrict__ s0, const float* __restrict__ s1,
                            const float* __restrict__ s2, const float* __restrict__ s3,
                            const float* __restrict__ s4, const float* __restrict__ s5,
                            const float* __restrict__ s6, const float* __restrict__ s7,
                            ushort* __restrict__ o) {
  unsigned i = blockIdx.x * 256u + threadIdx.x;
  if (i >= WS_ELEMS) return;
  float v;
  if (i < OW6) {
    unsigned m = i >> 18, r = i & 262143u;
    unsigned w = r >> 15, r2 = r & 32767u;
    unsigned k0i = r2 >> 12, r3 = r2 & 4095u;
    unsigned gs = r3 >> 9, r4 = r3 & 511u;
    unsigned lane = r4 >> 3, e = r4 & 7u;
    unsigned row = (gs >> 1) * 256u + (gs & 1u) * 16u + w * 32u + (lane & 15u);
    unsigned colk = k0i * 32u + (lane >> 4) * 8u + e;
    const float* s = (m==0)?s0:(m==1)?s1:(m==2)?s2:(m==3)?s3:(m==4)?s4:s5;
    v = s[row * 256u + colk];
  } else if (i < OW7) {
    unsigned r = i - OW6;
    unsigned w = r >> 12, r2 = r & 4095u;
    unsigned k0i = r2 >> 9, r3 = r2 & 511u;
    unsigned lane = r3 >> 3, e = r3 & 7u;
    unsigned row = w * 16u + (lane & 15u);
    unsigned colk = k0i * 32u + (lane >> 4) * 8u + e;
    v = s6[row * 256u + colk];
  } else {
    unsigned r = i - OW7;
    unsigned k0i = r >> 9, r3 = r & 511u;
    unsigned lane = r3 >> 3, e = r3 & 7u;
    unsigned row = lane & 15u;
    unsigned colk = k0i * 32u + (lane >> 4) * 8u + e;
    v = (row < 4u) ? s7[row * 128u + colk] : 0.0f;
  }
  __bf16 b = (__bf16)v;
  o[i] = __builtin_bit_cast(ushort, b);
}

__device__ __forceinline__ float sig_(float x) {
  return __builtin_amdgcn_rcpf(1.0f + __expf(-x));
}
__device__ __forceinline__ float tanh_(float x) {
  return 1.0f - 2.0f * __builtin_amdgcn_rcpf(__expf(2.0f*x) + 1.0f);
}
// 32-slot swizzle: granule u of row stored at slot (u + 4*(row&7)) & 31.
__device__ __forceinline__ int swz32(int row, int n) {
  return row*H_DIM + ((((n >> 3) + 4*(row & 7)) & 31) << 3) + (n & 7);
}
__device__ __forceinline__ bf16x8 ldh(const ushort* buf, int row, int u) {
  return *(const bf16x8*)(buf + row*H_DIM + (((u + 4*(row & 7)) & 31) << 3));
}

// load one 4-fragment weight chunk (wave-contiguous 1KB x 4, gate stride 1024)
#define LDW4(dst, Bb, k0i) { _Pragma("unroll") \
  for (int g = 0; g < 4; ++g) (dst)[g] = *(const bf16x8*)((Bb) + (k0i)*4096 + g*1024); }
#define MFMA4(acc, af, src) { _Pragma("unroll") \
  for (int g = 0; g < 4; ++g) (acc)[g] = __builtin_amdgcn_mfma_f32_16x16x32_bf16((af), (src)[g], (acc)[g], 0, 0, 0); }

#define GATES4(accv, cst, dst) { _Pragma("unroll") \
  for (int r = 0; r < 4; ++r) { \
    float iv = sig_((accv)[0][r]); \
    float fv = sig_((accv)[1][r]); \
    float gv = tanh_((accv)[2][r]); \
    float ov = sig_((accv)[3][r]); \
    float cn = fv*(cst)[r] + iv*gv; \
    (cst)[r] = cn; \
    float hn = ov*tanh_(cn); \
    __bf16 hb = (__bf16)hn; \
    (dst)[swz32(quad*4+r, n0)] = __builtin_bit_cast(ushort, hb); \
  } }

__global__ __launch_bounds__(NTH, 4) void lstm_all(
    const float* __restrict__ x,
    const float* __restrict__ eWih0, const float* __restrict__ eb0, const float* __restrict__ eb1,
    const float* __restrict__ dWih0, const float* __restrict__ db0, const float* __restrict__ db1,
    const float* __restrict__ bp1, const float* __restrict__ bp2,
    const ushort* __restrict__ ws,
    float* __restrict__ out)
{
  const int tid  = threadIdx.x;
  const int wv   = tid >> 6;      // wave 0..15
  const int lane = tid & 63;
  const int col  = lane & 15;
  const int quad = lane >> 4;
  const int blk  = blockIdx.x;
  const int n0   = wv*16 + col;   // this wave's 16-col slice within each gate
  const int rot  = blk & 7;

  __shared__ __align__(16) ushort sh_h0[2][BB*H_DIM];
  __shared__ __align__(16) ushort sh_h1[2][BB*H_DIM];
  __shared__ __align__(16) ushort sh_r[BB*H_DIM];
  __shared__ __align__(16) float  sh_x[SEQ*BB*4];   // [t][b][k]
  __shared__ __align__(16) float  sh_pred[BB*4];

  for (int i = tid; i < SEQ*BB*4; i += NTH) {
    int b = i >> 8, tk = i & 255;
    sh_x[(tk>>2)*64 + b*4 + (tk&3)] = x[blk*(SEQ*BB*4) + i];
  }
  for (int i = tid; i < BB*H_DIM; i += NTH) {
    sh_h0[0][i]=0; sh_h0[1][i]=0; sh_h1[0][i]=0; sh_h1[1][i]=0;
  }
  __syncthreads();

  float c0[4] = {0,0,0,0};
  float c1[4] = {0,0,0,0};
  int cur = 0;

  // per-lane fragment bases: slice (w=wv>>1, st=wv&1); fragment at +k0i*4096 + g*1024
  const unsigned sb = (unsigned)(wv>>1)*32768u + (unsigned)(wv&1)*512u + (unsigned)lane*8u;
  const ushort* B0 = ws + OW0 + sb;
  const ushort* B1 = ws + OW1 + sb;
  const ushort* B2 = ws + OW2 + sb;
  const ushort* B3 = ws + OW3 + sb;
  const ushort* B4 = ws + OW4 + sb;
  const ushort* B5 = ws + OW5 + sb;
  const ushort* B6 = ws + OW6 + (wv&7)*4096 + lane*8;   // MLP1: waves 0..7
  const ushort* B7 = ws + OW7 + lane*8;

  // ================= ENCODER =================
  {
    float eb0v[4], eb1v[4];
    #pragma unroll
    for (int g = 0; g < 4; ++g) {
      int j = g*256 + n0;
      eb0v[g] = eb0[j];
      eb1v[g] = eb1[j];
    }

    for (int t = 0; t < SEQ; ++t) {
      const ushort* h0c = sh_h0[cur];
      // acc init from x-projection (IN=4, VALU)
      f32x4 acc[4];
      {
        f32x4 xv[4];
        #pragma unroll
        for (int r = 0; r < 4; ++r)
          xv[r] = *(const f32x4*)(sh_x + t*64 + (quad*4+r)*4);
        #pragma unroll
        for (int g = 0; g < 4; ++g) {
          int j = g*256 + n0;
          f32x4 wvv = *(const f32x4*)(eWih0 + j*4);
          float bz = eb0v[g];
          #pragma unroll
          for (int r = 0; r < 4; ++r)
            acc[g][r] = bz + wvv[0]*xv[r][0] + wvv[1]*xv[r][1]
                           + wvv[2]*xv[r][2] + wvv[3]*xv[r][3];
        }
      }
      // ---- phase A: layer0 (B0 x h0c) ----
      #pragma unroll 2
      for (int it = 0; it < 8; ++it) {
        int k0i = (it + rot) & 7;
        bf16x8 bw[4]; LDW4(bw, B0, k0i);
        bf16x8 af = ldh(h0c, col, k0i*4 + quad);
        MFMA4(acc, af, bw);
      }
      ushort* h0n = sh_h0[cur^1];
      GATES4(acc, c0, h0n);
      __syncthreads();

      // ---- phase B: layer1 (B1 x h0n, B2 x h1c) ----
      f32x4 acc1[4];
      #pragma unroll
      for (int g = 0; g < 4; ++g) {
        float bz = eb1v[g];
        f32x4 v; v[0]=bz; v[1]=bz; v[2]=bz; v[3]=bz;
        acc1[g] = v;
      }
      #pragma unroll 2
      for (int it = 0; it < 8; ++it) {
        int k0i = (it + rot) & 7;
        bf16x8 bw[4]; LDW4(bw, B1, k0i);
        bf16x8 af = ldh(h0n, col, k0i*4 + quad);
        MFMA4(acc1, af, bw);
      }
      const ushort* h1c = sh_h1[cur];
      #pragma unroll 2
      for (int it = 0; it < 8; ++it) {
        int k0i = (it + rot) & 7;
        bf16x8 bw[4]; LDW4(bw, B2, k0i);
        bf16x8 af = ldh(h1c, col, k0i*4 + quad);
        MFMA4(acc1, af, bw);
      }
      ushort* h1n = sh_h1[cur^1];
      GATES4(acc1, c1, h1n);
      cur ^= 1;
    }
  }

  // ================= DECODER =================
  if (tid < 64) sh_pred[tid] = sh_x[63*64 + tid];
  __syncthreads();

  {
    float db0v[4], db1v[4];
    #pragma unroll
    for (int g = 0; g < 4; ++g) {
      int j = g*256 + n0;
      db0v[g] = db0[j];
      db1v[g] = db1[j];
    }
    const float bz1 = bp1[(wv&7)*16 + col];

    for (int t = 0; t < TDEC; ++t) {
      const ushort* h0c = sh_h0[cur];
      f32x4 acc[4];
      {
        f32x4 pv[4];
        #pragma unroll
        for (int r = 0; r < 4; ++r)
          pv[r] = *(const f32x4*)(sh_pred + (quad*4+r)*4);
        #pragma unroll
        for (int g = 0; g < 4; ++g) {
          int j = g*256 + n0;
          f32x4 wvv = *(const f32x4*)(dWih0 + j*4);
          float bz = db0v[g];
          #pragma unroll
          for (int r = 0; r < 4; ++r)
            acc[g][r] = bz + wvv[0]*pv[r][0] + wvv[1]*pv[r][1]
                           + wvv[2]*pv[r][2] + wvv[3]*pv[r][3];
        }
      }
      // ---- phase A: layer0 (B3 x h0c) ----
      #pragma unroll 2
      for (int it = 0; it < 8; ++it) {
        int k0i = (it + rot) & 7;
        bf16x8 bw[4]; LDW4(bw, B3, k0i);
        bf16x8 af = ldh(h0c, col, k0i*4 + quad);
        MFMA4(acc, af, bw);
      }
      ushort* h0n = sh_h0[cur^1];
      GATES4(acc, c0, h0n);
      __syncthreads();

      // ---- phase B: layer1 (B4 x h0n, B5 x h1c) ----
      f32x4 acc1[4];
      #pragma unroll
      for (int g = 0; g < 4; ++g) {
        float bz = db1v[g];
        f32x4 v; v[0]=bz; v[1]=bz; v[2]=bz; v[3]=bz;
        acc1[g] = v;
      }
      #pragma unroll 2
      for (int it = 0; it < 8; ++it) {
        int k0i = (it + rot) & 7;
        bf16x8 bw[4]; LDW4(bw, B4, k0i);
        bf16x8 af = ldh(h0n, col, k0i*4 + quad);
        MFMA4(acc1, af, bw);
      }
      const ushort* h1c = sh_h1[cur];
      #pragma unroll 2
      for (int it = 0; it < 8; ++it) {
        int k0i = (it + rot) & 7;
        bf16x8 bw[4]; LDW4(bw, B5, k0i);
        bf16x8 af = ldh(h1c, col, k0i*4 + quad);
        MFMA4(acc1, af, bw);
      }
      ushort* h1n = sh_h1[cur^1];
      GATES4(acc1, c1, h1n);
      __syncthreads();

      // ---- MLP layer 1 (waves 0..7; B6 x h1n) -> relu -> sh_r ----
      if (wv < 8) {
        f32x4 accp; accp[0]=bz1; accp[1]=bz1; accp[2]=bz1; accp[3]=bz1;
        #pragma unroll 2
        for (int j = 0; j < 8; ++j) {
          int k0i = (j+rot)&7;
          bf16x8 wp = *(const bf16x8*)(B6 + k0i*512);
          bf16x8 af = ldh(h1n, col, k0i*4 + quad);
          accp = __builtin_amdgcn_mfma_f32_16x16x32_bf16(af, wp, accp, 0, 0, 0);
        }
        #pragma unroll
        for (int r = 0; r < 4; ++r) {
          float rv = fmaxf(accp[r], 0.0f);
          __bf16 rb = (__bf16)rv;
          sh_r[swz32(quad*4+r, wv*16 + col)] = __builtin_bit_cast(ushort, rb);
        }
      }
      __syncthreads();

      // ---- MLP layer 2 (wave 0 only, B7) ----
      if (wv == 0) {
        f32x4 accq; accq[0]=0; accq[1]=0; accq[2]=0; accq[3]=0;
        #pragma unroll
        for (int j = 0; j < 4; ++j) {
          int k0i = (j+rot)&3;
          bf16x8 wq = *(const bf16x8*)(B7 + k0i*512);
          bf16x8 af = ldh(sh_r, col, k0i*4 + quad);
          accq = __builtin_amdgcn_mfma_f32_16x16x32_bf16(af, wq, accq, 0, 0, 0);
        }
        if (col < 4) {
          float bo = bp2[col];
          #pragma unroll
          for (int r = 0; r < 4; ++r) {
            float p = sig_(accq[r] + bo);
            int b = quad*4 + r;
            sh_pred[b*4 + col] = p;
            out[((blk*BB + b)*TDEC + t)*4 + col] = p;
          }
        }
      }
      __syncthreads();
      cur ^= 1;
    }
  }
}

extern "C" void kernel_launch(void* const* d_in, const int* in_sizes, int n_in,
                              void* d_out, int out_size, void* d_ws, size_t ws_size,
                              hipStream_t stream) {
  (void)in_sizes; (void)n_in; (void)out_size;
  if (ws_size < (size_t)WS_ELEMS * sizeof(ushort)) return;

  const float* x      = (const float*)d_in[0];
  const float* eWih0  = (const float*)d_in[1];
  const float* eWhh0  = (const float*)d_in[2];
  const float* eb0    = (const float*)d_in[3];
  const float* eWih1  = (const float*)d_in[4];
  const float* eWhh1  = (const float*)d_in[5];
  const float* eb1    = (const float*)d_in[6];
  const float* dWih0  = (const float*)d_in[7];
  const float* dWhh0  = (const float*)d_in[8];
  const float* db0    = (const float*)d_in[9];
  const float* dWih1  = (const float*)d_in[10];
  const float* dWhh1  = (const float*)d_in[11];
  const float* db1    = (const float*)d_in[12];
  const float* Wp1    = (const float*)d_in[13];
  const float* bp1    = (const float*)d_in[14];
  const float* Wp2    = (const float*)d_in[15];
  const float* bp2    = (const float*)d_in[16];
  ushort* ws = (ushort*)d_ws;

  prep_kernel<<<WS_ELEMS/256, 256, 0, stream>>>(eWhh0, eWih1, eWhh1, dWhh0, dWih1, dWhh1,
                                                Wp1, Wp2, ws);
  lstm_all<<<256, NTH, 0, stream>>>(x, eWih0, eb0, eb1, dWih0, db0, db1,
                                    bp1, bp2, ws, (float*)d_out);
}